// Round 3
// baseline (331.183 us; speedup 1.0000x reference)
//
#include <hip/hip_runtime.h>
#include <hip/hip_bf16.h>

// C[M,N] = A[M,K] @ B[N,K]^T, fp32 in/out, bf16 MFMA.
// Phase 1: fused fp32->bf16 convert of A,B into d_ws.
// Phase 2: 256x128/BK=64 GEMM, 256 thr = 4 waves 2Mx2N -> 128x64 wave tile
//   (24 ds_read_b128 per 64 MFMA/wave/tile = 0.375/MFMA, vs 0.5 for the
//   R2 64x64 tile: LDS read pipe ~1290 cyc/tile now balances MFMA 1242).
//   3-buffer LDS ring (144 KiB), depth-2 global_load_lds prefetch, ONE
//   barrier per K-tile: ring slack makes intra-tile barriers unnecessary
//   (buffer staged at top of tile t was last read in tile t-1; all waves
//   passed the t-1 boundary barrier). Tile body is barrier-free so the
//   compiler software-pipelines reads under MFMAs (fine-grained lgkmcnt).
//   Counted s_waitcnt vmcnt(12) placed before the LAST MFMA cluster so the
//   drain hides under MFMA; boundary barrier after. Tail drains vmcnt(0).
//   XOR bank-swizzle on 16B chunks (slot(c,row)=c^(row&7); staging lane
//   fetches pre-swizzled global chunk; measured 0 conflicts). XCD-bijective
//   block swizzle (FETCH_SIZE 266->65.6 MB = compulsory; HBM ~15%).

typedef __bf16 bf16x8 __attribute__((ext_vector_type(8)));
typedef float f32x4 __attribute__((ext_vector_type(4)));

#define BM 256
#define BN 128
#define BK 64
#define NBUF 3
// fallback tile
#define TM 128
#define TN 128

#define MFMA16(a_, b_, c_) \
    __builtin_amdgcn_mfma_f32_16x16x32_bf16((a_), (b_), (c_), 0, 0, 0)

__device__ __forceinline__ void load_lds16(const void* g, void* l) {
    __builtin_amdgcn_global_load_lds(
        (const __attribute__((address_space(1))) void*)g,
        (__attribute__((address_space(3))) void*)l,
        16 /*bytes*/, 0 /*offset*/, 0 /*aux*/);
}

// ---- fused convert: A then B, grid-stride.
__global__ void cvt_all(const float* __restrict__ A, uint4* __restrict__ Ao,
                        long nA8, const float* __restrict__ B,
                        uint4* __restrict__ Bo, long nB8) {
    const long stride = (long)gridDim.x * blockDim.x;
    const long tot = nA8 + nB8;
    for (long i = (long)blockIdx.x * blockDim.x + threadIdx.x; i < tot;
         i += stride) {
        const float4* p;
        uint4* d;
        if (i < nA8) {
            p = (const float4*)A + i * 2;
            d = Ao + i;
        } else {
            const long j = i - nA8;
            p = (const float4*)B + j * 2;
            d = Bo + j;
        }
        const float4 a = p[0];
        const float4 b = p[1];
        union { __hip_bfloat16 h[8]; uint4 u; } o;
        o.h[0] = __float2bfloat16(a.x); o.h[1] = __float2bfloat16(a.y);
        o.h[2] = __float2bfloat16(a.z); o.h[3] = __float2bfloat16(a.w);
        o.h[4] = __float2bfloat16(b.x); o.h[5] = __float2bfloat16(b.y);
        o.h[6] = __float2bfloat16(b.z); o.h[7] = __float2bfloat16(b.w);
        *d = o.u;
    }
}

__global__ __launch_bounds__(256, 1) void gemm_bt_pipe(
    const __bf16* __restrict__ A,  // [M,K] bf16
    const __bf16* __restrict__ B,  // [N,K] bf16
    float* __restrict__ C,         // [M,N] fp32
    int M, int N, int K) {
    __shared__ __bf16 As[NBUF * BM * BK];  // 96 KiB
    __shared__ __bf16 Bs[NBUF * BN * BK];  // 48 KiB

    const int tid = threadIdx.x;
    const int wave = tid >> 6;
    const int lane = tid & 63;

    // ---- XCD-bijective swizzle: XCD x owns a 4bm x 8bn chunk (~16 MB).
    const int nbn = N / BN;
    const int nbm = M / BM;
    const int L = (int)blockIdx.x;
    int bm, bn;
    if ((nbm & 7) == 0) {
        const int x = L & 7;
        const int s = L >> 3;
        bm = x * (nbm >> 3) + s / nbn;
        bn = s % nbn;
    } else {
        bm = L / nbn;
        bn = L % nbn;
    }

    // ---- staging: row = 128 B = 8 chunks; 256 threads cover 32 rows/round.
    // A tile = 8 rounds, B tile = 4 rounds; 12 loads/thread/K-tile.
    const int srow = tid >> 3;                    // row within round (0..31)
    const int schk = (tid & 7) ^ (srow & 7);      // pre-swizzled global chunk
    const __bf16* ga = A + ((size_t)bm * BM + srow) * (size_t)K + schk * 8;
    const __bf16* gb = B + ((size_t)bn * BN + srow) * (size_t)K + schk * 8;
    const size_t g32 = (size_t)32 * K;            // 32-row advance per round
    const int ldst = tid * 8;                     // LDS elem offset in round

    // ---- fragment addressing: wave (wr,wc) owns 128x64 at (wr*128, wc*64)
    const int wm = (wave >> 1) << 7;  // 0,128
    const int wn = (wave & 1) << 6;   // 0,64
    const int fr = lane & 15;
    const int qd = lane >> 4;
    const int r7 = fr & 7;
    const int sl0 = (qd ^ r7) << 3;        // swizzled slot, K-half 0 chunk qd
    const int sl1 = ((qd + 4) ^ r7) << 3;  // K-half 1 chunk qd+4

    f32x4 acc[8][4];
#pragma unroll
    for (int i = 0; i < 8; ++i)
#pragma unroll
        for (int j = 0; j < 4; ++j) acc[i][j] = (f32x4){0.f, 0.f, 0.f, 0.f};

    const int NT = K / BK;  // 64

    // ---- prologue: stage tiles 0 and 1 (12 loads each, tile-ordered)
#pragma unroll
    for (int r = 0; r < 8; ++r) load_lds16(ga + r * g32, As + ldst + r * 2048);
#pragma unroll
    for (int r = 0; r < 4; ++r) load_lds16(gb + r * g32, Bs + ldst + r * 2048);
    asm volatile("" ::: "memory");
#pragma unroll
    for (int r = 0; r < 8; ++r)
        load_lds16(ga + r * g32 + BK, As + BM * BK + ldst + r * 2048);
#pragma unroll
    for (int r = 0; r < 4; ++r)
        load_lds16(gb + r * g32 + BK, Bs + BN * BK + ldst + r * 2048);
    asm volatile("s_waitcnt vmcnt(12)" ::: "memory");  // tile 0 resident
    __builtin_amdgcn_s_barrier();
    asm volatile("" ::: "memory");

    int cur = 0, nx = 2;
    for (int t = 0; t < NT; ++t) {
        const __bf16* as = As + cur * (BM * BK);
        const __bf16* bs = Bs + cur * (BN * BK);
        __bf16* asw = As + nx * (BM * BK);
        __bf16* bsw = Bs + nx * (BN * BK);
        const bool pf = (t + 2 < NT);

        // ---- stage tile t+2 (buffer nx == (t-1)%3: all waves finished
        // reading it before the t-1 -> t boundary barrier).
        if (pf) {
            const size_t kg = (size_t)(t + 2) * BK;
#pragma unroll
            for (int r = 0; r < 8; ++r)
                load_lds16(ga + r * g32 + kg, asw + ldst + r * 2048);
#pragma unroll
            for (int r = 0; r < 4; ++r)
                load_lds16(gb + r * g32 + kg, bsw + ldst + r * 2048);
        }

        bf16x8 af[8], bf[4];
        // ---- K-half 0: 12 ds_read_b128, 32 MFMA (barrier-free region;
        // compiler pipelines half-1 reads under these MFMAs)
#pragma unroll
        for (int j = 0; j < 4; ++j)
            bf[j] = *(const bf16x8*)(bs + (wn + j * 16 + fr) * BK + sl0);
#pragma unroll
        for (int i = 0; i < 8; ++i)
            af[i] = *(const bf16x8*)(as + (wm + i * 16 + fr) * BK + sl0);
#pragma unroll
        for (int i = 0; i < 8; ++i)
#pragma unroll
            for (int j = 0; j < 4; ++j)
                acc[i][j] = MFMA16(af[i], bf[j], acc[i][j]);

        // ---- K-half 1 reads
        bf16x8 af1[8], bf1[4];
#pragma unroll
        for (int j = 0; j < 4; ++j)
            bf1[j] = *(const bf16x8*)(bs + (wn + j * 16 + fr) * BK + sl1);
#pragma unroll
        for (int i = 0; i < 8; ++i)
            af1[i] = *(const bf16x8*)(as + (wm + i * 16 + fr) * BK + sl1);

        // ---- counted drain BEFORE the last MFMA cluster: stall hides
        // under MFMA issue. Guarantees tile t+1's 12 oldest loads landed.
        if (t + 1 < NT) {
            if (pf) asm volatile("s_waitcnt vmcnt(12)" ::: "memory");
            else    asm volatile("s_waitcnt vmcnt(0)" ::: "memory");
        }

        // ---- K-half 1: 32 MFMA
#pragma unroll
        for (int i = 0; i < 8; ++i)
#pragma unroll
            for (int j = 0; j < 4; ++j)
                acc[i][j] = MFMA16(af1[i], bf1[j], acc[i][j]);

        // ---- tile boundary: single barrier publishes all waves' t+1
        // loads and bounds wave drift to < 1 tile (= ring slack).
        if (t + 1 < NT) {
            __builtin_amdgcn_s_barrier();
            asm volatile("" ::: "memory");
        }
        cur = (cur == NBUF - 1) ? 0 : cur + 1;
        nx = (nx == NBUF - 1) ? 0 : nx + 1;
    }

    // ---- epilogue: C/D layout col=lane&15, row=(lane>>4)*4+reg  [m89/m91]
    const int cq = qd << 2;
    float* Cbase = C + ((size_t)bm * BM + wm + cq) * (size_t)N +
                   (size_t)bn * BN + wn + fr;
#pragma unroll
    for (int i = 0; i < 8; ++i)
#pragma unroll
        for (int r = 0; r < 4; ++r) {
            float* row = Cbase + (size_t)(16 * i + r) * N;
#pragma unroll
            for (int j = 0; j < 4; ++j) row[16 * j] = acc[i][j][r];
        }
}

// Fallback if ws too small: fused-convert GEMM (BK=32), plain stores.
__global__ __launch_bounds__(256, 2) void gemm_bt_f32in(
    const float* __restrict__ A, const float* __restrict__ B,
    float* __restrict__ C, int M, int N, int K) {
    __shared__ __bf16 As[TM * 32];
    __shared__ __bf16 Bs[TN * 32];

    const int tid = threadIdx.x;
    const int wave = tid >> 6;
    const int lane = tid & 63;
    const int bn = blockIdx.x;
    const int bm = blockIdx.y;

    const int frow = tid >> 3;
    const int fcol = (tid & 7) << 2;
    const float* gaf = A + ((size_t)bm * TM + frow) * (size_t)K + fcol;
    const float* gbf = B + ((size_t)bn * TN + frow) * (size_t)K + fcol;

    const int wm = (wave >> 1) << 6;
    const int wn = (wave & 1) << 6;
    const int fr = lane & 15;
    const int fk = (lane >> 4) << 3;
    const __bf16* pa = As + (wm + fr) * 32 + fk;
    const __bf16* pb = Bs + (wn + fr) * 32 + fk;

    f32x4 acc[4][4];
#pragma unroll
    for (int i = 0; i < 4; ++i)
#pragma unroll
        for (int j = 0; j < 4; ++j) acc[i][j] = (f32x4){0.f, 0.f, 0.f, 0.f};

    for (int k0 = 0; k0 < K; k0 += 32) {
#pragma unroll
        for (int rd = 0; rd < 4; ++rd) {
            float4 va = *(const float4*)(gaf + (size_t)(rd * 32) * K + k0);
            float4 vb = *(const float4*)(gbf + (size_t)(rd * 32) * K + k0);
            union { __hip_bfloat162 h2[2]; uint2 u; } oa, ob;
            oa.h2[0] = __float22bfloat162_rn(make_float2(va.x, va.y));
            oa.h2[1] = __float22bfloat162_rn(make_float2(va.z, va.w));
            ob.h2[0] = __float22bfloat162_rn(make_float2(vb.x, vb.y));
            ob.h2[1] = __float22bfloat162_rn(make_float2(vb.z, vb.w));
            *(uint2*)(As + (frow + rd * 32) * 32 + fcol) = oa.u;
            *(uint2*)(Bs + (frow + rd * 32) * 32 + fcol) = ob.u;
        }
        __syncthreads();

        bf16x8 af[4], bfr[4];
#pragma unroll
        for (int i = 0; i < 4; ++i) af[i] = *(const bf16x8*)(pa + i * (16 * 32));
#pragma unroll
        for (int j = 0; j < 4; ++j) bfr[j] = *(const bf16x8*)(pb + j * (16 * 32));
#pragma unroll
        for (int i = 0; i < 4; ++i)
#pragma unroll
            for (int j = 0; j < 4; ++j)
                acc[i][j] = __builtin_amdgcn_mfma_f32_16x16x32_bf16(
                    af[i], bfr[j], acc[i][j], 0, 0, 0);
        __syncthreads();
    }

    const int cq = (lane >> 4) << 2;
    float* Cbase = C + ((size_t)bm * TM + wm + cq) * (size_t)N +
                   (size_t)bn * TN + wn + fr;
#pragma unroll
    for (int i = 0; i < 4; ++i)
#pragma unroll
        for (int r = 0; r < 4; ++r) {
            float* row = Cbase + (size_t)(16 * i + r) * N;
#pragma unroll
            for (int j = 0; j < 4; ++j) row[16 * j] = acc[i][j][r];
        }
}

extern "C" void kernel_launch(void* const* d_in, const int* in_sizes, int n_in,
                              void* d_out, int out_size, void* d_ws,
                              size_t ws_size, hipStream_t stream) {
    const float* A = (const float*)d_in[0];  // [M,K] (all_gather = reshape)
    const float* B = (const float*)d_in[1];  // [N,K]
    float* C = (float*)d_out;

    const int K = 4096;
    const int aN = in_sizes[0];
    const int bN = in_sizes[1];
    const int M = aN / K;  // 8192
    const int N = bN / K;  // 1024

    const size_t need = ((size_t)aN + (size_t)bN) * sizeof(__hip_bfloat16);

    if (ws_size >= need && (M % BM) == 0 && (N % BN) == 0) {
        __hip_bfloat16* Abf = (__hip_bfloat16*)d_ws;
        __hip_bfloat16* Bbf = Abf + (size_t)aN;
        cvt_all<<<2048, 256, 0, stream>>>(A, (uint4*)Abf, (long)(aN / 8), B,
                                          (uint4*)Bbf, (long)(bN / 8));
        dim3 grid((unsigned)((M / BM) * (N / BN)));  // 256 = 1 block/CU
        gemm_bt_pipe<<<grid, 256, 0, stream>>>((const __bf16*)Abf,
                                               (const __bf16*)Bbf, C, M, N, K);
    } else {
        dim3 grid(N / TN, M / TM);
        gemm_bt_f32in<<<grid, 256, 0, stream>>>(A, B, C, M, N, K);
    }
}

// Round 4
// 276.710 us; speedup vs baseline: 1.1969x; 1.1969x over previous
//
#include <hip/hip_runtime.h>
#include <hip/hip_bf16.h>

// C[M,N] = A[M,K] @ B[N,K]^T, fp32 in/out, bf16 MFMA.
// Phase 1: fused fp32->bf16 convert of A,B into d_ws.
// Phase 2: 256x128/BK=64 GEMM, 512 thr = 8 waves, grid 256 = 1 block/CU,
//   2 waves/SIMD (R3 lesson: 1 wave/SIMD is fatal).
//   K-SPLIT WAVE PAIRS: 4 spatial 128x64 wave tiles x 2 K-halves. Wave
//   (s=wave&3, wk=wave>>2) computes spatial tile s over chunks 4wk..4wk+3
//   of each BK=64 step: 12 ds_read_b128 per 32 MFMA (m201's 0.375 ratio;
//   CU-wide 96 reads/tile vs R2's 128 -> -25% LDS-read pipe). Cross-wave
//   reduction once at end: wk=1 waves write acc to LDS, wk=0 add (~1K cyc).
//   3-buffer LDS ring (144 KiB), depth-2 global_load_lds prefetch, ONE
//   barrier per K-tile (ring slack bounds drift; buffer staged at tile t
//   was last read at t-1, published by the t-1 boundary barrier). Counted
//   s_waitcnt vmcnt(6) at boundary (6 loads/thread/tile in flight), never
//   0 until tail. Single 32-MFMA cluster/wave/tile wrapped in setprio.
//   XOR bank-swizzle on 16B chunks (slot(c,row)=c^(row&7); staging lane
//   fetches pre-swizzled global chunk; measured 0 conflicts). XCD-bijective
//   block swizzle (FETCH_SIZE 266->65.6 MB = compulsory).

typedef __bf16 bf16x8 __attribute__((ext_vector_type(8)));
typedef float f32x4 __attribute__((ext_vector_type(4)));

#define BM 256
#define BN 128
#define BK 64
#define NBUF 3
// fallback tile
#define TM 128
#define TN 128

#define MFMA16(a_, b_, c_) \
    __builtin_amdgcn_mfma_f32_16x16x32_bf16((a_), (b_), (c_), 0, 0, 0)

__device__ __forceinline__ void load_lds16(const void* g, void* l) {
    __builtin_amdgcn_global_load_lds(
        (const __attribute__((address_space(1))) void*)g,
        (__attribute__((address_space(3))) void*)l,
        16 /*bytes*/, 0 /*offset*/, 0 /*aux*/);
}

// ---- fused convert: A then B, grid-stride.
__global__ void cvt_all(const float* __restrict__ A, uint4* __restrict__ Ao,
                        long nA8, const float* __restrict__ B,
                        uint4* __restrict__ Bo, long nB8) {
    const long stride = (long)gridDim.x * blockDim.x;
    const long tot = nA8 + nB8;
    for (long i = (long)blockIdx.x * blockDim.x + threadIdx.x; i < tot;
         i += stride) {
        const float4* p;
        uint4* d;
        if (i < nA8) {
            p = (const float4*)A + i * 2;
            d = Ao + i;
        } else {
            const long j = i - nA8;
            p = (const float4*)B + j * 2;
            d = Bo + j;
        }
        const float4 a = p[0];
        const float4 b = p[1];
        union { __hip_bfloat16 h[8]; uint4 u; } o;
        o.h[0] = __float2bfloat16(a.x); o.h[1] = __float2bfloat16(a.y);
        o.h[2] = __float2bfloat16(a.z); o.h[3] = __float2bfloat16(a.w);
        o.h[4] = __float2bfloat16(b.x); o.h[5] = __float2bfloat16(b.y);
        o.h[6] = __float2bfloat16(b.z); o.h[7] = __float2bfloat16(b.w);
        *d = o.u;
    }
}

__global__ __launch_bounds__(512, 2) void gemm_bt_pipe(
    const __bf16* __restrict__ A,  // [M,K] bf16
    const __bf16* __restrict__ B,  // [N,K] bf16
    float* __restrict__ C,         // [M,N] fp32
    int M, int N, int K) {
    // single smem block: ring buffers in the loop, reduction scratch after.
    __shared__ __align__(16) unsigned char smem[147456];  // 144 KiB
    __bf16* As = (__bf16*)smem;                  // 3 * 256*64*2 = 96 KiB
    __bf16* Bs = (__bf16*)(smem + 98304);        // 3 * 128*64*2 = 48 KiB

    const int tid = threadIdx.x;
    const int wave = tid >> 6;
    const int lane = tid & 63;

    // ---- XCD-bijective swizzle: XCD x owns a 4bm x 8bn chunk (~16 MB).
    const int nbn = N / BN;
    const int nbm = M / BM;
    const int L = (int)blockIdx.x;
    int bm, bn;
    if ((nbm & 7) == 0) {
        const int x = L & 7;
        const int s = L >> 3;
        bm = x * (nbm >> 3) + s / nbn;
        bn = s % nbn;
    } else {
        bm = L / nbn;
        bn = L % nbn;
    }

    // ---- staging: row = 128 B = 8 chunks; 512 threads cover 64 rows/round.
    // A tile = 4 rounds, B tile = 2 rounds; 6 loads/thread/K-tile.
    const int srow = tid >> 3;                    // row within round (0..63)
    const int schk = (tid & 7) ^ (srow & 7);      // pre-swizzled global chunk
    const __bf16* ga = A + ((size_t)bm * BM + srow) * (size_t)K + schk * 8;
    const __bf16* gb = B + ((size_t)bn * BN + srow) * (size_t)K + schk * 8;
    const size_t g64 = (size_t)64 * K;            // 64-row advance per round
    const int ldst = tid * 8;                     // LDS elem offset in round

    // ---- fragment addressing: spatial slot s = wave&3 -> 128x64 tile at
    // (s>>1)*128, (s&1)*64; K-half wk = wave>>2 -> chunks 4wk..4wk+3.
    const int ws = wave & 3;
    const int wk = wave >> 2;
    const int wm = (ws >> 1) << 7;    // 0,128
    const int wn = (ws & 1) << 6;     // 0,64
    const int fr = lane & 15;
    const int qd = lane >> 4;
    const int r7 = fr & 7;
    const int sl = (((qd + 4 * wk)) ^ r7) << 3;   // swizzled 16B slot

    f32x4 acc[8][4];
#pragma unroll
    for (int i = 0; i < 8; ++i)
#pragma unroll
        for (int j = 0; j < 4; ++j) acc[i][j] = (f32x4){0.f, 0.f, 0.f, 0.f};

    const int NT = K / BK;  // 64

    // ---- prologue: stage tiles 0 and 1 (6 loads each, tile-ordered)
#pragma unroll
    for (int r = 0; r < 4; ++r) load_lds16(ga + r * g64, As + ldst + r * 4096);
#pragma unroll
    for (int r = 0; r < 2; ++r) load_lds16(gb + r * g64, Bs + ldst + r * 4096);
    asm volatile("" ::: "memory");
#pragma unroll
    for (int r = 0; r < 4; ++r)
        load_lds16(ga + r * g64 + BK, As + BM * BK + ldst + r * 4096);
#pragma unroll
    for (int r = 0; r < 2; ++r)
        load_lds16(gb + r * g64 + BK, Bs + BN * BK + ldst + r * 4096);
    asm volatile("s_waitcnt vmcnt(6)" ::: "memory");  // tile 0 resident
    __builtin_amdgcn_s_barrier();
    asm volatile("" ::: "memory");

    int cur = 0, nx = 2;
    for (int t = 0; t < NT; ++t) {
        const __bf16* as = As + cur * (BM * BK);
        const __bf16* bs = Bs + cur * (BN * BK);
        __bf16* asw = As + nx * (BM * BK);
        __bf16* bsw = Bs + nx * (BN * BK);
        const bool pf = (t + 2 < NT);

        // ---- fragment reads: 12 ds_read_b128 (critical path first)
        bf16x8 af[8], bf[4];
#pragma unroll
        for (int j = 0; j < 4; ++j)
            bf[j] = *(const bf16x8*)(bs + (wn + j * 16 + fr) * BK + sl);
#pragma unroll
        for (int i = 0; i < 8; ++i)
            af[i] = *(const bf16x8*)(as + (wm + i * 16 + fr) * BK + sl);

        // ---- stage tile t+2 into buffer (t-1)%3 (read finished at t-1,
        // published by the t-1 boundary barrier).
        if (pf) {
            const size_t kg = (size_t)(t + 2) * BK;
#pragma unroll
            for (int r = 0; r < 4; ++r)
                load_lds16(ga + r * g64 + kg, asw + ldst + r * 4096);
#pragma unroll
            for (int r = 0; r < 2; ++r)
                load_lds16(gb + r * g64 + kg, bsw + ldst + r * 4096);
        }

        // ---- single 32-MFMA cluster (all independent; K-half wk)
        __builtin_amdgcn_s_setprio(1);
#pragma unroll
        for (int i = 0; i < 8; ++i)
#pragma unroll
            for (int j = 0; j < 4; ++j)
                acc[i][j] = MFMA16(af[i], bf[j], acc[i][j]);
        __builtin_amdgcn_s_setprio(0);

        // ---- tile boundary: counted per-wave drain, then barrier
        // publishes all waves' t+1 loads; fence pins next-tile reads.
        if (t + 1 < NT) {
            if (pf) asm volatile("s_waitcnt vmcnt(6)" ::: "memory");
            else    asm volatile("s_waitcnt vmcnt(0)" ::: "memory");
            __builtin_amdgcn_s_barrier();
            asm volatile("" ::: "memory");
        }
        cur = (cur == NBUF - 1) ? 0 : cur + 1;
        nx = (nx == NBUF - 1) ? 0 : nx + 1;
    }

    // ---- cross-wave K-reduction: wk=1 waves dump acc, wk=0 partners add.
    // Reuses ring LDS (4 x 32 KiB = 128 KiB <= 144 KiB). __syncthreads is
    // safe here (outside hot loop; full waitcnt semantics wanted).
    float* red = (float*)smem;
    __syncthreads();
    if (wk == 1) {
        float* dst = red + ws * 8192;  // 32 KiB region per spatial slot
#pragma unroll
        for (int i = 0; i < 8; ++i)
#pragma unroll
            for (int j = 0; j < 4; ++j)
                *(f32x4*)(dst + (i * 4 + j) * 256 + lane * 4) = acc[i][j];
    }
    __syncthreads();
    if (wk == 0) {
        const float* src = red + ws * 8192;
#pragma unroll
        for (int i = 0; i < 8; ++i)
#pragma unroll
            for (int j = 0; j < 4; ++j) {
                f32x4 v = *(const f32x4*)(src + (i * 4 + j) * 256 + lane * 4);
                acc[i][j] += v;
            }

        // ---- epilogue: C/D layout col=lane&15, row=(lane>>4)*4+reg
        const int cq = qd << 2;
        float* Cbase = C + ((size_t)bm * BM + wm + cq) * (size_t)N +
                       (size_t)bn * BN + wn + fr;
#pragma unroll
        for (int i = 0; i < 8; ++i)
#pragma unroll
            for (int r = 0; r < 4; ++r) {
                float* row = Cbase + (size_t)(16 * i + r) * N;
#pragma unroll
                for (int j = 0; j < 4; ++j) row[16 * j] = acc[i][j][r];
            }
    }
}

// Fallback if ws too small: fused-convert GEMM (BK=32), plain stores.
__global__ __launch_bounds__(256, 2) void gemm_bt_f32in(
    const float* __restrict__ A, const float* __restrict__ B,
    float* __restrict__ C, int M, int N, int K) {
    __shared__ __bf16 As[TM * 32];
    __shared__ __bf16 Bs[TN * 32];

    const int tid = threadIdx.x;
    const int wave = tid >> 6;
    const int lane = tid & 63;
    const int bn = blockIdx.x;
    const int bm = blockIdx.y;

    const int frow = tid >> 3;
    const int fcol = (tid & 7) << 2;
    const float* gaf = A + ((size_t)bm * TM + frow) * (size_t)K + fcol;
    const float* gbf = B + ((size_t)bn * TN + frow) * (size_t)K + fcol;

    const int wm = (wave >> 1) << 6;
    const int wn = (wave & 1) << 6;
    const int fr = lane & 15;
    const int fk = (lane >> 4) << 3;
    const __bf16* pa = As + (wm + fr) * 32 + fk;
    const __bf16* pb = Bs + (wn + fr) * 32 + fk;

    f32x4 acc[4][4];
#pragma unroll
    for (int i = 0; i < 4; ++i)
#pragma unroll
        for (int j = 0; j < 4; ++j) acc[i][j] = (f32x4){0.f, 0.f, 0.f, 0.f};

    for (int k0 = 0; k0 < K; k0 += 32) {
#pragma unroll
        for (int rd = 0; rd < 4; ++rd) {
            float4 va = *(const float4*)(gaf + (size_t)(rd * 32) * K + k0);
            float4 vb = *(const float4*)(gbf + (size_t)(rd * 32) * K + k0);
            union { __hip_bfloat162 h2[2]; uint2 u; } oa, ob;
            oa.h2[0] = __float22bfloat162_rn(make_float2(va.x, va.y));
            oa.h2[1] = __float22bfloat162_rn(make_float2(va.z, va.w));
            ob.h2[0] = __float22bfloat162_rn(make_float2(vb.x, vb.y));
            ob.h2[1] = __float22bfloat162_rn(make_float2(vb.z, vb.w));
            *(uint2*)(As + (frow + rd * 32) * 32 + fcol) = oa.u;
            *(uint2*)(Bs + (frow + rd * 32) * 32 + fcol) = ob.u;
        }
        __syncthreads();

        bf16x8 af[4], bfr[4];
#pragma unroll
        for (int i = 0; i < 4; ++i) af[i] = *(const bf16x8*)(pa + i * (16 * 32));
#pragma unroll
        for (int j = 0; j < 4; ++j) bfr[j] = *(const bf16x8*)(pb + j * (16 * 32));
#pragma unroll
        for (int i = 0; i < 4; ++i)
#pragma unroll
            for (int j = 0; j < 4; ++j)
                acc[i][j] = __builtin_amdgcn_mfma_f32_16x16x32_bf16(
                    af[i], bfr[j], acc[i][j], 0, 0, 0);
        __syncthreads();
    }

    const int cq = (lane >> 4) << 2;
    float* Cbase = C + ((size_t)bm * TM + wm + cq) * (size_t)N +
                   (size_t)bn * TN + wn + fr;
#pragma unroll
    for (int i = 0; i < 4; ++i)
#pragma unroll
        for (int r = 0; r < 4; ++r) {
            float* row = Cbase + (size_t)(16 * i + r) * N;
#pragma unroll
            for (int j = 0; j < 4; ++j) row[16 * j] = acc[i][j][r];
        }
}

extern "C" void kernel_launch(void* const* d_in, const int* in_sizes, int n_in,
                              void* d_out, int out_size, void* d_ws,
                              size_t ws_size, hipStream_t stream) {
    const float* A = (const float*)d_in[0];  // [M,K] (all_gather = reshape)
    const float* B = (const float*)d_in[1];  // [N,K]
    float* C = (float*)d_out;

    const int K = 4096;
    const int aN = in_sizes[0];
    const int bN = in_sizes[1];
    const int M = aN / K;  // 8192
    const int N = bN / K;  // 1024

    const size_t need = ((size_t)aN + (size_t)bN) * sizeof(__hip_bfloat16);

    if (ws_size >= need && (M % BM) == 0 && (N % BN) == 0) {
        __hip_bfloat16* Abf = (__hip_bfloat16*)d_ws;
        __hip_bfloat16* Bbf = Abf + (size_t)aN;
        cvt_all<<<2048, 256, 0, stream>>>(A, (uint4*)Abf, (long)(aN / 8), B,
                                          (uint4*)Bbf, (long)(bN / 8));
        dim3 grid((unsigned)((M / BM) * (N / BN)));  // 256 = 1 block/CU
        gemm_bt_pipe<<<grid, 512, 0, stream>>>((const __bf16*)Abf,
                                               (const __bf16*)Bbf, C, M, N, K);
    } else {
        dim3 grid(N / TN, M / TM);
        gemm_bt_f32in<<<grid, 256, 0, stream>>>(A, B, C, M, N, K);
    }
}